// Round 3
// baseline (123.610 us; speedup 1.0000x reference)
//
#include <hip/hip_runtime.h>
#include <hip/hip_bf16.h>

// GATConv reduces algebraically to a permuted-column GEMM:
//   out[n, c] = sum_k x[n,k] * W[(c%8)*64 + c/8, k] + bias[c]
// (the reference einsum contracts alpha over its softmax axis -> sum == 1).
// N=4096, K=256, M=512.
//
// R3: single launch (R2's extra dispatch cost +7.5 us), but keep R2's
// winning structure: barrier-free, LDS-free, wave-independent GEMM with
// the fp32->bf16 conversion fused in-register. Each wave owns a 16x16
// output tile: 16 float4 A-loads + 16 float4 perm'd-W B-loads straight
// from fp32 global (L1/L2/L3-resident: x=4MB, W=0.5MB), ~64 pk-cvt VALU
// ops, 8 x mfma_f32_16x16x32_bf16, 4 stores. No LDS, no syncthreads, no
// workspace. Grid (16,128)=2048 blocks (vs 512 before) -> 4x the
// latency-hiding; __launch_bounds__(256,4) caps VGPR at 128 for
// 4 waves/SIMD with a deeply preloaded unrolled K-loop.

typedef __attribute__((ext_vector_type(8))) short bf16x8;   // 8 bf16 (4 VGPRs)
typedef __attribute__((ext_vector_type(4))) float floatx4;  // MFMA accumulator

__device__ __forceinline__ short f2bf(float f) {
    union { __hip_bfloat16 h; short s; } u;
    u.h = __float2bfloat16(f);   // RNE
    return u.s;
}

__global__ __launch_bounds__(256, 4) void gat_gemm(
    const float* __restrict__ x,    // [4096, 256]
    const float* __restrict__ W,    // [512, 256]
    const float* __restrict__ bias, // [512]
    float* __restrict__ out)        // [4096, 512]
{
    const int tid  = threadIdx.x;
    const int wv   = tid >> 6;          // 0..3
    const int lane = tid & 63;
    const int mrow = lane & 15;         // A row / output col within tile
    const int quad = lane >> 4;         // k-subblock (input), row-subblock (output)

    // 4 waves arranged 2x2 -> block covers 32x32 of out (L1 locality).
    const int rowBase = blockIdx.y * 32 + (wv >> 1) * 16;
    const int colBase = blockIdx.x * 32 + (wv & 1) * 16;

    // A fragment source: x[rowBase+mrow][kb*32 + quad*8 ..]
    // B fragment source: W[perm(colBase+mrow)][kb*32 + quad*8 ..]
    // (identical fragment layout to the LDS version verified in R0/R1,
    //  just sourced from fp32 global with in-register conversion).
    const int col  = colBase + mrow;
    const int wrow = ((col & 7) << 6) + (col >> 3);   // perm(col)
    const float* ap = &x[(rowBase + mrow) * 256 + quad * 8];
    const float* bp = &W[wrow * 256 + quad * 8];

    floatx4 acc = {0.f, 0.f, 0.f, 0.f};
    #pragma unroll
    for (int kb = 0; kb < 8; ++kb) {
        float4 a0 = *(const float4*)(ap + kb * 32);
        float4 a1 = *(const float4*)(ap + kb * 32 + 4);
        float4 b0 = *(const float4*)(bp + kb * 32);
        float4 b1 = *(const float4*)(bp + kb * 32 + 4);
        bf16x8 af, bf;
        af[0] = f2bf(a0.x); af[1] = f2bf(a0.y); af[2] = f2bf(a0.z); af[3] = f2bf(a0.w);
        af[4] = f2bf(a1.x); af[5] = f2bf(a1.y); af[6] = f2bf(a1.z); af[7] = f2bf(a1.w);
        bf[0] = f2bf(b0.x); bf[1] = f2bf(b0.y); bf[2] = f2bf(b0.z); bf[3] = f2bf(b0.w);
        bf[4] = f2bf(b1.x); bf[5] = f2bf(b1.y); bf[6] = f2bf(b1.z); bf[7] = f2bf(b1.w);
        acc = __builtin_amdgcn_mfma_f32_16x16x32_bf16(af, bf, acc, 0, 0, 0);
    }

    // C/D layout: col = lane&15 (= mrow), row = quad*4 + r
    const float bv = bias[col];
    #pragma unroll
    for (int r = 0; r < 4; ++r) {
        int row = rowBase + quad * 4 + r;
        out[row * 512 + col] = acc[r] + bv;
    }
}

extern "C" void kernel_launch(void* const* d_in, const int* in_sizes, int n_in,
                              void* d_out, int out_size, void* d_ws, size_t ws_size,
                              hipStream_t stream) {
    // setup_inputs order: 0=adj (unused), 1=x, 2=W, 3=att_src (unused),
    //                     4=att_dst (unused), 5=bias
    const float* x    = (const float*)d_in[1];
    const float* W    = (const float*)d_in[2];
    const float* bias = (const float*)d_in[5];
    float* out        = (float*)d_out;

    dim3 grid(512 / 32, 4096 / 32);  // (16, 128) = 2048 blocks
    dim3 block(256);
    hipLaunchKernelGGL(gat_gemm, grid, block, 0, stream, x, W, bias, out);
}

// Round 4
// 105.506 us; speedup vs baseline: 1.1716x; 1.1716x over previous
//
#include <hip/hip_runtime.h>
#include <hip/hip_bf16.h>

// GATConv reduces algebraically to a permuted-column GEMM:
//   out[n, c] = sum_k x[n,k] * W[(c%8)*64 + c/8, k] + bias[c]
// (the reference einsum contracts alpha over its softmax axis -> sum == 1).
// N=4096, K=256, M=512.
//
// R4: R1's structure (A global->reg, B staged once per block in LDS with
// 4-wave reuse) was work-efficient but latency-exposed: 512 blocks = only
// 2 blocks/CU. R3 proved per-wave-redundant staging (4x loads, 4x cvt) is
// worse. This round keeps R1's work efficiency and doubles parallelism:
// BN=32, BM=64 -> grid (16,64) = 1024 blocks = 4 blocks/CU = 16 waves/CU.
// Each wave owns 16 rows x 32 cols (2 MFMA tiles). W staging traffic is
// unchanged vs R1 (32 MB fp32 total); x redundancy x16 = 64 MB, L2-resident.
// LDS 16.9 KB/block; __launch_bounds__(256,4) caps VGPR at 128.

typedef __attribute__((ext_vector_type(8))) short bf16x8;   // 8 bf16 (4 VGPRs)
typedef __attribute__((ext_vector_type(4))) float floatx4;  // MFMA accumulator

#define BM 64
#define BN 32
#define LDK 264   // row stride in bf16 elems: 264*2B = 528B -> 4-bank/row advance, 16B-aligned rows

__device__ __forceinline__ short f2bf(float f) {
    union { __hip_bfloat16 h; short s; } u;
    u.h = __float2bfloat16(f);   // RNE
    return u.s;
}

__global__ __launch_bounds__(256, 4) void gat_gemm(
    const float* __restrict__ x,    // [4096, 256]
    const float* __restrict__ W,    // [512, 256]
    const float* __restrict__ bias, // [512]
    float* __restrict__ out)        // [4096, 512]
{
    __shared__ short Bs[BN][LDK];   // permuted-W tile, bf16 (B^T row-major)

    const int tid = threadIdx.x;       // 0..255
    const int rowBase = blockIdx.y * BM;
    const int colBase = blockIdx.x * BN;

    const int wave = tid >> 6;         // 0..3
    const int lane = tid & 63;
    const int mrow = lane & 15;        // row within wave's A slab / col within B tile
    const int quad = lane >> 4;        // 0..3 -> k-subblock (input), row-subblock (output)
    const int arow = wave * 16 + mrow;

    // ---- A: global -> registers (no LDS round trip; zero cross-wave reuse) ----
    const float* xrow = &x[(rowBase + arow) * 256 + quad * 8];
    float4 a[16];
    #pragma unroll
    for (int kb = 0; kb < 8; ++kb) {
        a[2 * kb]     = *(const float4*)(xrow + kb * 32);
        a[2 * kb + 1] = *(const float4*)(xrow + kb * 32 + 4);
    }

    // hoist bias (latency hidden under the stage phase)
    float bv0 = bias[colBase + 0 * 16 + mrow];
    float bv1 = bias[colBase + 1 * 16 + mrow];

    // ---- B stage: 32x256 fp32 -> bf16 into LDS (once per block, 4-wave reuse) ----
    // 32*256/4 = 2048 float4 per tile; 8 float4/thread.
    #pragma unroll
    for (int l = 0; l < 8; ++l) {
        int f  = tid + l * 256;    // float4 index 0..2047
        int r  = f >> 6;           // tile row 0..31
        int c4 = f & 63;           // float4 within row (k/4)
        int col  = colBase + r;
        int wrow = ((col & 7) << 6) + (col >> 3);    // perm(col)
        float4 bv = *(const float4*)&W[wrow * 256 + c4 * 4];
        short4 b; b.x = f2bf(bv.x); b.y = f2bf(bv.y); b.z = f2bf(bv.z); b.w = f2bf(bv.w);
        *(short4*)&Bs[r][c4 * 4] = b;
    }

    // ---- convert A in-register (A loads landed under the B stage) ----
    bf16x8 afrag[8];
    #pragma unroll
    for (int kb = 0; kb < 8; ++kb) {
        bf16x8 t;
        t[0] = f2bf(a[2 * kb].x);     t[1] = f2bf(a[2 * kb].y);
        t[2] = f2bf(a[2 * kb].z);     t[3] = f2bf(a[2 * kb].w);
        t[4] = f2bf(a[2 * kb + 1].x); t[5] = f2bf(a[2 * kb + 1].y);
        t[6] = f2bf(a[2 * kb + 1].z); t[7] = f2bf(a[2 * kb + 1].w);
        afrag[kb] = t;
    }

    __syncthreads();

    // ---- compute: each wave -> 16 rows x 32 cols = 2 MFMA col-tiles ----
    floatx4 acc0 = {0.f, 0.f, 0.f, 0.f};
    floatx4 acc1 = {0.f, 0.f, 0.f, 0.f};

    #pragma unroll
    for (int kb = 0; kb < 8; ++kb) {
        int koff = kb * 32 + quad * 8;                 // bf16 elem offset, 16B-aligned
        bf16x8 b0 = *(const bf16x8*)&Bs[mrow][koff];
        bf16x8 b1 = *(const bf16x8*)&Bs[16 + mrow][koff];
        acc0 = __builtin_amdgcn_mfma_f32_16x16x32_bf16(afrag[kb], b0, acc0, 0, 0, 0);
        acc1 = __builtin_amdgcn_mfma_f32_16x16x32_bf16(afrag[kb], b1, acc1, 0, 0, 0);
    }

    // ---- epilogue: C/D layout col=lane&15, row=quad*4+reg ----
    {
        int col = colBase + mrow;
        #pragma unroll
        for (int r = 0; r < 4; ++r) {
            int row = rowBase + wave * 16 + quad * 4 + r;
            out[row * 512 + col] = acc0[r] + bv0;
        }
    }
    {
        int col = colBase + 16 + mrow;
        #pragma unroll
        for (int r = 0; r < 4; ++r) {
            int row = rowBase + wave * 16 + quad * 4 + r;
            out[row * 512 + col] = acc1[r] + bv1;
        }
    }
}

extern "C" void kernel_launch(void* const* d_in, const int* in_sizes, int n_in,
                              void* d_out, int out_size, void* d_ws, size_t ws_size,
                              hipStream_t stream) {
    // setup_inputs order: 0=adj (unused), 1=x, 2=W, 3=att_src (unused),
    //                     4=att_dst (unused), 5=bias
    const float* x    = (const float*)d_in[1];
    const float* W    = (const float*)d_in[2];
    const float* bias = (const float*)d_in[5];
    float* out        = (float*)d_out;

    dim3 grid(512 / BN, 4096 / BM);  // (16, 64) = 1024 blocks
    dim3 block(256);
    hipLaunchKernelGGL(gat_gemm, grid, block, 0, stream, x, W, bias, out);
}